// Round 7
// baseline (171.909 us; speedup 1.0000x reference)
//
#include <hip/hip_runtime.h>
#include <hip/hip_bf16.h>

typedef __attribute__((ext_vector_type(8))) short bf16x8;
typedef __attribute__((ext_vector_type(4))) float f32x4;
typedef unsigned short u16;

#define B_  2
#define T_  2048
#define C_  1024
#define H_  16
#define HD_ 64

static __device__ __forceinline__ u16 f2bf(float f) {
  unsigned u = __float_as_uint(f);
  u += 0x7fffu + ((u >> 16) & 1u);   // round-to-nearest-even
  return (u16)(u >> 16);
}

// ---------------------------------------------------------------------------
// Kernel 0 "prep": three independent jobs fused into one dispatch
//   [0,6144):  convert X,W fp32->bf16 (float4 vectorized)
//   [6144,7168): pack V (=x per head) into MFMA-fragment layout Vf
//   [7168,7680): scanA: 16-row partial sums SubP16 + 128-row sums SubP128
// ---------------------------------------------------------------------------
#define NX4 1048576   // X float4 count
#define NW4 524288    // W float4 count
__global__ __launch_bounds__(256) void prep(
    const float* __restrict__ X, const float* __restrict__ W,
    u16* __restrict__ Xb, u16* __restrict__ Wb,
    u16* __restrict__ Vf, float* __restrict__ SubP16, float* __restrict__ SubP128)
{
  __shared__ __align__(16) char shb[8320];
  const int blk = blockIdx.x;
  const int tid = threadIdx.x;

  if (blk < 6144) {                       // ---- convert ----
    int i = blk * 256 + tid;
    if (i < NX4) {
      float4 v = ((const float4*)X)[i];
      ushort4 u = { f2bf(v.x), f2bf(v.y), f2bf(v.z), f2bf(v.w) };
      ((ushort4*)Xb)[i] = u;
    } else {
      int j = i - NX4;
      float4 v = ((const float4*)W)[j];
      ushort4 u = { f2bf(v.x), f2bf(v.y), f2bf(v.z), f2bf(v.w) };
      ((ushort4*)Wb)[j] = u;
    }
  } else if (blk < 7168) {                // ---- pack_vf ----
    u16 (*tr)[65] = (u16(*)[65])shb;
    int idx = blk - 6144;
    const int kt = idx & 31, bh = idx >> 5;
    const int b = bh >> 4, h = bh & 15;
    {
      const int row = tid >> 2;
      const int c0  = (tid & 3) * 16;
      const float* xp = X + ((size_t)b * T_ + kt * 64 + row) * C_ + h * 64 + c0;
#pragma unroll
      for (int q = 0; q < 4; ++q) {
        float4 v = *(const float4*)(xp + q * 4);
        tr[row][c0 + q * 4 + 0] = f2bf(v.x);
        tr[row][c0 + q * 4 + 1] = f2bf(v.y);
        tr[row][c0 + q * 4 + 2] = f2bf(v.z);
        tr[row][c0 + q * 4 + 3] = f2bf(v.w);
      }
    }
    __syncthreads();
    const int w = tid >> 6, lane = tid & 63, quad = (lane >> 4), l16 = lane & 15;
    u16* outb = Vf + ((size_t)bh * 32 + kt) * 4096;
#pragma unroll
    for (int c = 0; c < 2; ++c) {   // wave w = nb
      u16 tmp[8];
#pragma unroll
      for (int j = 0; j < 8; ++j) tmp[j] = tr[c * 32 + quad * 8 + j][w * 16 + l16];
      *(bf16x8*)&outb[((w * 2 + c) * 64 + lane) * 8] = *(const bf16x8*)tmp;
    }
  } else {                                // ---- scanA ----
    float* cs = (float*)shb;
    int idx = blk - 7168;
    const int ch = idx & 15, bh = idx >> 4;
    const int b = bh >> 4, h = bh & 15;
    const int d = tid & 63, s = tid >> 6;
    const float* xp = X + (size_t)b * T_ * C_ + h * 64 + d;
    int t0 = ch * 128 + s * 32;
    float sa = 0.f, sb = 0.f;
#pragma unroll 4
    for (int i = 0; i < 16; ++i) sa += xp[(size_t)(t0 + i) * C_];
#pragma unroll 4
    for (int i = 16; i < 32; ++i) sb += xp[(size_t)(t0 + i) * C_];
    SubP16[((size_t)bh * 128 + ch * 8 + s * 2) * 64 + d] = sa;
    SubP16[((size_t)bh * 128 + ch * 8 + s * 2 + 1) * 64 + d] = sb;
    cs[s * 64 + d] = sa + sb;
    __syncthreads();
    if (s == 0)
      SubP128[((size_t)bh * 16 + ch) * 64 + d] =
          cs[d] + cs[64 + d] + cs[128 + d] + cs[192 + d];
  }
}

// ---------------------------------------------------------------------------
// Kernel 1: qk = Xb @ Wb^T  (M=4096,N=2048,K=1024), 128x128 tile, BK=64,
// global_load_lds width=16. Q row-major [B,H,T,hd] PRE-SCALED by 0.125
// (exact pow2, folded out of attn); K into MFMA-B-fragment-linear Kf.
// Epilogue address math hoisted per (i,j): stores use small strides.
// ---------------------------------------------------------------------------
__global__ __launch_bounds__(256) void gemm_qk(
    const u16* __restrict__ Xb, const u16* __restrict__ Wb,
    u16* __restrict__ Qo, u16* __restrict__ Kf)
{
  __shared__ __align__(16) u16 As[128 * 64];
  __shared__ __align__(16) u16 Bs[128 * 64];

  const int tid  = threadIdx.x;
  const int w    = tid >> 6;
  const int lane = tid & 63;
  const int quad = lane >> 4;
  const int l16  = lane & 15;
  const int m0 = blockIdx.y * 128;
  const int n0 = blockIdx.x * 128;

  const int grow = w * 8 + ((lane >> 3) & 7);
  const int gcol = (lane & 7) * 8;

  f32x4 zero = {0.f, 0.f, 0.f, 0.f};
  f32x4 acc[4][4];
#pragma unroll
  for (int i = 0; i < 4; ++i)
#pragma unroll
    for (int j = 0; j < 4; ++j) acc[i][j] = zero;

  const int wr = (w >> 1) * 64, wc = (w & 1) * 64;

  for (int k0 = 0; k0 < C_; k0 += 64) {
#pragma unroll
    for (int r = 0; r < 4; ++r) {
      const u16* ga = Xb + (size_t)(m0 + grow + r * 32) * C_ + k0 + gcol;
      const u16* gb = Wb + (size_t)(n0 + grow + r * 32) * C_ + k0 + gcol;
      __builtin_amdgcn_global_load_lds(
          (const __attribute__((address_space(1))) void*)ga,
          (__attribute__((address_space(3))) void*)&As[(w * 8 + r * 32) * 64],
          16, 0, 0);
      __builtin_amdgcn_global_load_lds(
          (const __attribute__((address_space(1))) void*)gb,
          (__attribute__((address_space(3))) void*)&Bs[(w * 8 + r * 32) * 64],
          16, 0, 0);
    }
    __syncthreads();
#pragma unroll
    for (int c = 0; c < 2; ++c) {
      bf16x8 af[4], bf[4];
#pragma unroll
      for (int i = 0; i < 4; ++i)
        af[i] = *(const bf16x8*)&As[(wr + i * 16 + l16) * 64 + c * 32 + quad * 8];
#pragma unroll
      for (int j = 0; j < 4; ++j)
        bf[j] = *(const bf16x8*)&Bs[(wc + j * 16 + l16) * 64 + c * 32 + quad * 8];
#pragma unroll
      for (int i = 0; i < 4; ++i)
#pragma unroll
        for (int j = 0; j < 4; ++j)
          acc[i][j] = __builtin_amdgcn_mfma_f32_16x16x32_bf16(af[i], bf[j], acc[i][j], 0, 0, 0);
    }
    __syncthreads();
  }

  // C/D layout: col = lane&15, row = quad*4 + reg (verified m89/m91)
#pragma unroll
  for (int i = 0; i < 4; ++i) {
    const int t_base = m0 + wr + i * 16;       // 16-aligned
    const int bidx = t_base >> 11;
    const int kt   = (t_base & 2047) >> 6;
    const int trow = (t_base & 2047) + quad * 4;
#pragma unroll
    for (int j = 0; j < 4; ++j) {
      const int n = n0 + wc + j * 16 + l16;    // wave-uniform branch base
      if (n < C_) {
        const int hq = n >> 6, d = n & 63;
        u16* qp = Qo + (((size_t)bidx * H_ + hq) * T_ + trow) * HD_ + d;
#pragma unroll
        for (int r = 0; r < 4; ++r) qp[(size_t)r * HD_] = f2bf(0.125f * acc[i][j][r]);
      } else {
        const int nh = n - C_;
        const int hh = nh >> 6, d = nh & 63;
        u16* kp = Kf + (((((size_t)(bidx * H_ + hh) * 32 + kt) * 4 + i) * 2 + (d >> 5)) * 64
                        + ((d >> 3) & 3) * 16 + quad * 4) * 8 + (d & 7);
#pragma unroll
        for (int r = 0; r < 4; ++r) kp[(size_t)r * 8] = f2bf(acc[i][j][r]);
      }
    }
  }
}

// ---------------------------------------------------------------------------
// Kernel 2: flash attention, 2 waves per 16 q-rows splitting kt even/odd
// (softmax-no-max is associative), peeled diagonal tile, fragment-linear
// K/V loads, LDS combine, fully fused scan+alpha/gamma epilogue.
// ---------------------------------------------------------------------------
__device__ __forceinline__ void load_kv(
    bf16x8 (&kf)[2][4], bf16x8 (&vf)[2][4],
    const u16* __restrict__ kbase, const u16* __restrict__ vbase, int lane)
{
#pragma unroll
  for (int c = 0; c < 2; ++c)
#pragma unroll
    for (int nb = 0; nb < 4; ++nb) {
      kf[c][nb] = *(const bf16x8*)&kbase[((nb * 2 + c) * 64 + lane) * 8];
      vf[c][nb] = *(const bf16x8*)&vbase[((nb * 2 + c) * 64 + lane) * 8];
    }
}

__device__ __forceinline__ void tile_compute(
    const bf16x8 (&qfrag)[2], const bf16x8 (&kf)[2][4], const bf16x8 (&vf)[2][4],
    f32x4 (&acc)[4], f32x4& accl, float (*pb)[68],
    int quad, int l16, int wrow, bool diag, bf16x8 onesf)
{
  f32x4 zero = {0.f, 0.f, 0.f, 0.f};
  f32x4 sfr[4] = {zero, zero, zero, zero};
#pragma unroll
  for (int cc = 0; cc < 2; ++cc)
#pragma unroll
    for (int nb = 0; nb < 4; ++nb)
      sfr[nb] = __builtin_amdgcn_mfma_f32_16x16x32_bf16(qfrag[cc], kf[cc][nb], sfr[nb], 0, 0, 0);

  if (diag) {
#pragma unroll
    for (int nb = 0; nb < 4; ++nb)
#pragma unroll
      for (int r = 0; r < 4; ++r) {
        float p = __expf(sfr[nb][r]);
        if (nb * 16 + l16 > wrow + quad * 4 + r) p = 0.f;
        pb[quad * 4 + r][nb * 16 + l16] = p;
      }
  } else {
#pragma unroll
    for (int nb = 0; nb < 4; ++nb)
#pragma unroll
      for (int r = 0; r < 4; ++r)
        pb[quad * 4 + r][nb * 16 + l16] = __expf(sfr[nb][r]);
  }

#pragma unroll
  for (int cc = 0; cc < 2; ++cc) {
    f32x4 plo = *(const f32x4*)&pb[l16][cc * 32 + quad * 8];
    f32x4 phi = *(const f32x4*)&pb[l16][cc * 32 + quad * 8 + 4];
    union { unsigned u[4]; bf16x8 v; } pk;
    __hip_bfloat162 hh;
    hh = __float22bfloat162_rn(make_float2(plo[0], plo[1])); pk.u[0] = *(unsigned*)&hh;
    hh = __float22bfloat162_rn(make_float2(plo[2], plo[3])); pk.u[1] = *(unsigned*)&hh;
    hh = __float22bfloat162_rn(make_float2(phi[0], phi[1])); pk.u[2] = *(unsigned*)&hh;
    hh = __float22bfloat162_rn(make_float2(phi[2], phi[3])); pk.u[3] = *(unsigned*)&hh;
    accl = __builtin_amdgcn_mfma_f32_16x16x32_bf16(pk.v, onesf, accl, 0, 0, 0);
#pragma unroll
    for (int nb = 0; nb < 4; ++nb)
      acc[nb] = __builtin_amdgcn_mfma_f32_16x16x32_bf16(pk.v, vf[cc][nb], acc[nb], 0, 0, 0);
  }
}

__global__ __launch_bounds__(128) void attn_kernel(
    const u16* __restrict__ Q, const u16* __restrict__ Kf, const u16* __restrict__ Vf,
    const float* __restrict__ SubP16, const float* __restrict__ SubP128,
    const float* __restrict__ X, float* __restrict__ out,
    const float* __restrict__ alphap, const float* __restrict__ betap,
    const float* __restrict__ gammap)
{
  __shared__ __align__(16) float pbs[2][16][68];
  __shared__ float redl[16];

  const int tid  = threadIdx.x;
  const int p    = tid >> 6;             // kt-parity this wave owns
  const int lane = tid & 63;
  const int quad = lane >> 4;
  const int l16  = lane & 15;
  const int qt = 31 - blockIdx.y;        // LPT
  const int w  = blockIdx.z;             // 16-row group within the 64-row qt tile
  const int bh = blockIdx.x;
  const int b = bh >> 4, h = bh & 15;
  const int wrow  = w * 16;
  const int qrow0 = qt * 64 + wrow;

  const u16* kfb = Kf + (size_t)bh * T_ * HD_;
  const u16* vfb = Vf + (size_t)bh * T_ * HD_;

  bf16x8 qfrag[2];
  {
    const u16* qp = Q + ((size_t)bh * T_ + qrow0 + l16) * HD_ + quad * 8;
    qfrag[0] = *(const bf16x8*)qp;
    qfrag[1] = *(const bf16x8*)(qp + 32);
  }

  bf16x8 onesf;
#pragma unroll
  for (int j = 0; j < 8; ++j) onesf[j] = (short)0x3F80;

  f32x4 zero = {0.f, 0.f, 0.f, 0.f};
  f32x4 acc[4] = {zero, zero, zero, zero};
  f32x4 accl = zero;
  float (*pb)[68] = pbs[p];

  const bool hasDiag = ((qt & 1) == p);
  const int n = (qt - p + 1) >> 1;       // count of my non-diag tiles (kt = p+2i)
  const int total = n + (hasDiag ? 1 : 0);

  if (total > 0) {
    const int D = total - 1;
    bf16x8 kA[2][4], vA[2][4], kB[2][4], vB[2][4];
    int k0 = (0 < n) ? p : qt;
    load_kv(kA, vA, kfb + (size_t)k0 * 4096, vfb + (size_t)k0 * 4096, lane);
    int i = 0;
    while (i + 2 <= D) {
      int k1 = (i + 1 < n) ? p + 2 * (i + 1) : qt;
      load_kv(kB, vB, kfb + (size_t)k1 * 4096, vfb + (size_t)k1 * 4096, lane);
      tile_compute(qfrag, kA, vA, acc, accl, pb, quad, l16, wrow, false, onesf);
      int k2 = (i + 2 < n) ? p + 2 * (i + 2) : qt;
      load_kv(kA, vA, kfb + (size_t)k2 * 4096, vfb + (size_t)k2 * 4096, lane);
      tile_compute(qfrag, kB, vB, acc, accl, pb, quad, l16, wrow, false, onesf);
      i += 2;
    }
    if (i < D) {
      int k1 = (i + 1 < n) ? p + 2 * (i + 1) : qt;
      load_kv(kB, vB, kfb + (size_t)k1 * 4096, vfb + (size_t)k1 * 4096, lane);
      tile_compute(qfrag, kA, vA, acc, accl, pb, quad, l16, wrow, false, onesf);
      tile_compute(qfrag, kB, vB, acc, accl, pb, quad, l16, wrow, hasDiag, onesf);
    } else {
      tile_compute(qfrag, kA, vA, acc, accl, pb, quad, l16, wrow, hasDiag, onesf);
    }
  }

  // ---- combine the two kt-halves (wave1 -> LDS, wave0 reduces) ----
  if (p == 1) {
#pragma unroll
    for (int nb = 0; nb < 4; ++nb)
#pragma unroll
      for (int r = 0; r < 4; ++r)
        pbs[1][quad * 4 + r][nb * 16 + l16] = acc[nb][r];
    if (l16 == 0) {
#pragma unroll
      for (int r = 0; r < 4; ++r) redl[quad * 4 + r] = accl[r];
    }
  }
  __syncthreads();
  if (p == 1) return;

#pragma unroll
  for (int nb = 0; nb < 4; ++nb)
#pragma unroll
    for (int r = 0; r < 4; ++r)
      acc[nb][r] += pbs[1][quad * 4 + r][nb * 16 + l16];
#pragma unroll
  for (int r = 0; r < 4; ++r) accl[r] += redl[quad * 4 + r];

  // ---- fused epilogue: out = beta*att + alpha*x - gamma*prefix/(t+1) ----
  float xv[4][4];
  const float* xb = X + ((size_t)b * T_ + qrow0) * C_ + h * 64;
#pragma unroll
  for (int nb = 0; nb < 4; ++nb)
#pragma unroll
    for (int r = 0; r < 4; ++r)
      xv[nb][r] = xb[(size_t)(quad * 4 + r) * C_ + nb * 16 + l16];

  const int g16 = qt * 4 + w;
  float base[4];
#pragma unroll
  for (int nb = 0; nb < 4; ++nb) {
    float loc = xv[nb][0] + xv[nb][1] + xv[nb][2] + xv[nb][3];
    float p1 = __shfl(loc, (lane - 16) & 63);
    float p2 = __shfl(loc, (lane - 32) & 63);
    float p3 = __shfl(loc, (lane - 48) & 63);
    float e = 0.f;
    if (quad > 0) e += p1;
    if (quad > 1) e += p2;
    if (quad > 2) e += p3;
    const int col = nb * 16 + l16;
    const float* p128 = SubP128 + (size_t)bh * 16 * 64 + col;
    const float* p16  = SubP16  + (size_t)bh * 128 * 64 + col;
    for (int j = 0; j < (g16 >> 3); ++j) e += p128[(size_t)j * 64];
    for (int k = g16 & ~7; k < g16; ++k) e += p16[(size_t)k * 64];
    base[nb] = e;
  }

  const float alpha = *alphap, beta = *betap, gamma = *gammap;
  float rl[4];
#pragma unroll
  for (int r = 0; r < 4; ++r) rl[r] = beta * __builtin_amdgcn_rcpf(accl[r]);
#pragma unroll
  for (int nb = 0; nb < 4; ++nb) {
    float run = base[nb];
#pragma unroll
    for (int r = 0; r < 4; ++r) {
      run += xv[nb][r];
      int t = qrow0 + quad * 4 + r;
      out[((size_t)b * T_ + t) * C_ + h * 64 + nb * 16 + l16] =
          alpha * xv[nb][r] - gamma * run * __builtin_amdgcn_rcpf((float)(t + 1))
          + rl[r] * acc[nb][r];
    }
  }
}

// ---------------------------------------------------------------------------
extern "C" void kernel_launch(void* const* d_in, const int* in_sizes, int n_in,
                              void* d_out, int out_size, void* d_ws, size_t ws_size,
                              hipStream_t stream) {
  const float* x      = (const float*)d_in[0];
  const float* W_attn = (const float*)d_in[1];
  const float* alphap = (const float*)d_in[2];
  const float* betap  = (const float*)d_in[3];
  const float* gammap = (const float*)d_in[4];
  float* out = (float*)d_out;

  // ws: Qb@0(8M) Kf@8(8M) Vf@16(8M) SubP16@24(1M) SubP128@25(.125M)
  //     Xb@26(8M) Wb@34(4M)  -> 38MB
  char* ws = (char*)d_ws;
  u16*   Qb    = (u16*)(ws);
  u16*   Kfb   = (u16*)(ws + (8ull  << 20));
  u16*   Vfb   = (u16*)(ws + (16ull << 20));
  float* SubP16  = (float*)(ws + (24ull << 20));
  float* SubP128 = (float*)(ws + (25ull << 20));
  u16*   Xb    = (u16*)(ws + (26ull << 20));
  u16*   Wb    = (u16*)(ws + (34ull << 20));

  prep<<<7680, 256, 0, stream>>>(x, W_attn, Xb, Wb, Vfb, SubP16, SubP128);
  gemm_qk<<<dim3(16, 32), 256, 0, stream>>>(Xb, Wb, Qb, Kfb);
  attn_kernel<<<dim3(32, 32, 4), 128, 0, stream>>>(Qb, Kfb, Vfb, SubP16, SubP128,
                                                   x, out, alphap, betap, gammap);
}

// Round 8
// 151.771 us; speedup vs baseline: 1.1327x; 1.1327x over previous
//
#include <hip/hip_runtime.h>
#include <hip/hip_bf16.h>

typedef __attribute__((ext_vector_type(8))) short bf16x8;
typedef __attribute__((ext_vector_type(4))) float f32x4;
typedef unsigned short u16;

#define B_  2
#define T_  2048
#define C_  1024
#define H_  16
#define HD_ 64

static __device__ __forceinline__ u16 f2bf(float f) {
  unsigned u = __float_as_uint(f);
  u += 0x7fffu + ((u >> 16) & 1u);   // round-to-nearest-even
  return (u16)(u >> 16);
}

// ---------------------------------------------------------------------------
// Kernel 0 "prep": two regions in one dispatch
//   [0,1024):   pack block (bh,kt): read 64x64 X tile fp32 once ->
//               Xb (bf16 row-major), Vf (MFMA-fragment layout), and
//               SubP64[bh][kt][d] = column sums (fp32, via xor-shuffles)
//   [1024,3072): convert W fp32->bf16 (float4 vectorized)
// ---------------------------------------------------------------------------
#define NW4 524288    // W float4 count
__global__ __launch_bounds__(256) void prep(
    const float* __restrict__ X, const float* __restrict__ W,
    u16* __restrict__ Xb, u16* __restrict__ Wb,
    u16* __restrict__ Vf, float* __restrict__ SubP64)
{
  __shared__ u16 tr[64][65];
  __shared__ float cs[4][64];
  const int blk = blockIdx.x;
  const int tid = threadIdx.x;

  if (blk < 1024) {                       // ---- pack + convert-X + colsums ----
    const int kt = blk & 31, bh = blk >> 5;
    const int b = bh >> 4, h = bh & 15;
    const int w = tid >> 6, lane = tid & 63;
    {
      const int row = tid >> 2;            // 0..63
      const int c0  = (tid & 3) * 16;      // float col base
      const float* xp = X + ((size_t)b * T_ + kt * 64 + row) * C_ + h * 64 + c0;
      float vals[16];
#pragma unroll
      for (int q = 0; q < 4; ++q) {
        float4 v = *(const float4*)(xp + q * 4);
        vals[q * 4 + 0] = v.x; vals[q * 4 + 1] = v.y;
        vals[q * 4 + 2] = v.z; vals[q * 4 + 3] = v.w;
      }
      // bf16 convert once; feed Xb and tr
      u16 xb[16];
#pragma unroll
      for (int i = 0; i < 16; ++i) xb[i] = f2bf(vals[i]);
      u16* xq = Xb + ((size_t)(b * T_ + kt * 64 + row)) * C_ + h * 64 + c0;
      *(bf16x8*)xq       = *(const bf16x8*)&xb[0];
      *(bf16x8*)(xq + 8) = *(const bf16x8*)&xb[8];
#pragma unroll
      for (int i = 0; i < 16; ++i) tr[row][c0 + i] = xb[i];
      // column sums over this wave's 16 rows (lanes sharing (lane&3))
#pragma unroll
      for (int m = 4; m <= 32; m <<= 1)
#pragma unroll
        for (int i = 0; i < 16; ++i) vals[i] += __shfl_xor(vals[i], m);
      if (lane < 4) {
        float* dst = &cs[w][lane * 16];
#pragma unroll
        for (int q = 0; q < 4; ++q) {
          f32x4 s4 = { vals[q * 4 + 0], vals[q * 4 + 1], vals[q * 4 + 2], vals[q * 4 + 3] };
          *(f32x4*)&dst[q * 4] = s4;
        }
      }
    }
    __syncthreads();
    // Vf transpose (wave w = nb)
    {
      const int quad = (lane >> 4), l16 = lane & 15;
      u16* outb = Vf + ((size_t)bh * 32 + kt) * 4096;
#pragma unroll
      for (int c = 0; c < 2; ++c) {
        u16 tmp[8];
#pragma unroll
        for (int j = 0; j < 8; ++j) tmp[j] = tr[c * 32 + quad * 8 + j][w * 16 + l16];
        *(bf16x8*)&outb[((w * 2 + c) * 64 + lane) * 8] = *(const bf16x8*)tmp;
      }
    }
    if (tid < 64)
      SubP64[(size_t)bh * 2048 + kt * 64 + tid] =
          cs[0][tid] + cs[1][tid] + cs[2][tid] + cs[3][tid];
  } else {                                // ---- convert W ----
    int i = (blk - 1024) * 256 + tid;
    float4 v = ((const float4*)W)[i];
    ushort4 u = { f2bf(v.x), f2bf(v.y), f2bf(v.z), f2bf(v.w) };
    ((ushort4*)Wb)[i] = u;
  }
}

// ---------------------------------------------------------------------------
// Kernel 1: qk = Xb @ Wb^T  (M=4096,N=2048,K=1024), 128x128 tile, BK=64,
// global_load_lds width=16. Q row-major [B,H,T,hd] PRE-SCALED by 0.125
// (exact pow2, folded out of attn); K into MFMA-B-fragment-linear Kf.
// ---------------------------------------------------------------------------
__global__ __launch_bounds__(256) void gemm_qk(
    const u16* __restrict__ Xb, const u16* __restrict__ Wb,
    u16* __restrict__ Qo, u16* __restrict__ Kf)
{
  __shared__ __align__(16) u16 As[128 * 64];
  __shared__ __align__(16) u16 Bs[128 * 64];

  const int tid  = threadIdx.x;
  const int w    = tid >> 6;
  const int lane = tid & 63;
  const int quad = lane >> 4;
  const int l16  = lane & 15;
  const int m0 = blockIdx.y * 128;
  const int n0 = blockIdx.x * 128;

  const int grow = w * 8 + ((lane >> 3) & 7);
  const int gcol = (lane & 7) * 8;

  f32x4 zero = {0.f, 0.f, 0.f, 0.f};
  f32x4 acc[4][4];
#pragma unroll
  for (int i = 0; i < 4; ++i)
#pragma unroll
    for (int j = 0; j < 4; ++j) acc[i][j] = zero;

  const int wr = (w >> 1) * 64, wc = (w & 1) * 64;

  for (int k0 = 0; k0 < C_; k0 += 64) {
#pragma unroll
    for (int r = 0; r < 4; ++r) {
      const u16* ga = Xb + (size_t)(m0 + grow + r * 32) * C_ + k0 + gcol;
      const u16* gb = Wb + (size_t)(n0 + grow + r * 32) * C_ + k0 + gcol;
      __builtin_amdgcn_global_load_lds(
          (const __attribute__((address_space(1))) void*)ga,
          (__attribute__((address_space(3))) void*)&As[(w * 8 + r * 32) * 64],
          16, 0, 0);
      __builtin_amdgcn_global_load_lds(
          (const __attribute__((address_space(1))) void*)gb,
          (__attribute__((address_space(3))) void*)&Bs[(w * 8 + r * 32) * 64],
          16, 0, 0);
    }
    __syncthreads();
#pragma unroll
    for (int c = 0; c < 2; ++c) {
      bf16x8 af[4], bf[4];
#pragma unroll
      for (int i = 0; i < 4; ++i)
        af[i] = *(const bf16x8*)&As[(wr + i * 16 + l16) * 64 + c * 32 + quad * 8];
#pragma unroll
      for (int j = 0; j < 4; ++j)
        bf[j] = *(const bf16x8*)&Bs[(wc + j * 16 + l16) * 64 + c * 32 + quad * 8];
#pragma unroll
      for (int i = 0; i < 4; ++i)
#pragma unroll
        for (int j = 0; j < 4; ++j)
          acc[i][j] = __builtin_amdgcn_mfma_f32_16x16x32_bf16(af[i], bf[j], acc[i][j], 0, 0, 0);
    }
    __syncthreads();
  }

  // C/D layout: col = lane&15, row = quad*4 + reg (verified m89/m91)
#pragma unroll
  for (int i = 0; i < 4; ++i) {
    const int t_base = m0 + wr + i * 16;       // 16-aligned
    const int bidx = t_base >> 11;
    const int kt   = (t_base & 2047) >> 6;
    const int trow = (t_base & 2047) + quad * 4;
#pragma unroll
    for (int j = 0; j < 4; ++j) {
      const int n = n0 + wc + j * 16 + l16;    // wave-uniform branch base
      if (n < C_) {
        const int hq = n >> 6, d = n & 63;
        u16* qp = Qo + (((size_t)bidx * H_ + hq) * T_ + trow) * HD_ + d;
#pragma unroll
        for (int r = 0; r < 4; ++r) qp[(size_t)r * HD_] = f2bf(0.125f * acc[i][j][r]);
      } else {
        const int nh = n - C_;
        const int hh = nh >> 6, d = nh & 63;
        u16* kp = Kf + (((((size_t)(bidx * H_ + hh) * 32 + kt) * 4 + i) * 2 + (d >> 5)) * 64
                        + ((d >> 3) & 3) * 16 + quad * 4) * 8 + (d & 7);
#pragma unroll
        for (int r = 0; r < 4; ++r) kp[(size_t)r * 8] = f2bf(acc[i][j][r]);
      }
    }
  }
}

// ---------------------------------------------------------------------------
// Kernel 2: software-pipelined barrier-free flash attention + fused epilogue
// (round-6 structure; Q pre-scaled so no score multiply; SubP64 prefix base).
// ---------------------------------------------------------------------------
__device__ __forceinline__ void load_kv(
    bf16x8 (&kf)[2][4], bf16x8 (&vf)[2][4],
    const u16* __restrict__ kbase, const u16* __restrict__ vbase, int lane)
{
#pragma unroll
  for (int c = 0; c < 2; ++c)
#pragma unroll
    for (int nb = 0; nb < 4; ++nb) {
      kf[c][nb] = *(const bf16x8*)&kbase[((nb * 2 + c) * 64 + lane) * 8];
      vf[c][nb] = *(const bf16x8*)&vbase[((nb * 2 + c) * 64 + lane) * 8];
    }
}

__device__ __forceinline__ void tile_compute(
    const bf16x8 (&qfrag)[2], const bf16x8 (&kf)[2][4], const bf16x8 (&vf)[2][4],
    f32x4 (&acc)[4], f32x4& accl, float (*pb)[68],
    int quad, int l16, int myrow, bool diag, bf16x8 onesf)
{
  f32x4 zero = {0.f, 0.f, 0.f, 0.f};
  f32x4 sfr[4] = {zero, zero, zero, zero};
#pragma unroll
  for (int cc = 0; cc < 2; ++cc)
#pragma unroll
    for (int nb = 0; nb < 4; ++nb)
      sfr[nb] = __builtin_amdgcn_mfma_f32_16x16x32_bf16(qfrag[cc], kf[cc][nb], sfr[nb], 0, 0, 0);

#pragma unroll
  for (int nb = 0; nb < 4; ++nb)
#pragma unroll
    for (int r = 0; r < 4; ++r) {
      float p = __expf(sfr[nb][r]);
      if (diag && (nb * 16 + l16 > myrow + r)) p = 0.f;
      pb[quad * 4 + r][nb * 16 + l16] = p;
    }

#pragma unroll
  for (int cc = 0; cc < 2; ++cc) {
    f32x4 plo = *(const f32x4*)&pb[l16][cc * 32 + quad * 8];
    f32x4 phi = *(const f32x4*)&pb[l16][cc * 32 + quad * 8 + 4];
    union { unsigned u[4]; bf16x8 v; } pk;
    __hip_bfloat162 hh;
    hh = __float22bfloat162_rn(make_float2(plo[0], plo[1])); pk.u[0] = *(unsigned*)&hh;
    hh = __float22bfloat162_rn(make_float2(plo[2], plo[3])); pk.u[1] = *(unsigned*)&hh;
    hh = __float22bfloat162_rn(make_float2(phi[0], phi[1])); pk.u[2] = *(unsigned*)&hh;
    hh = __float22bfloat162_rn(make_float2(phi[2], phi[3])); pk.u[3] = *(unsigned*)&hh;
    accl = __builtin_amdgcn_mfma_f32_16x16x32_bf16(pk.v, onesf, accl, 0, 0, 0);
#pragma unroll
    for (int nb = 0; nb < 4; ++nb)
      acc[nb] = __builtin_amdgcn_mfma_f32_16x16x32_bf16(pk.v, vf[cc][nb], acc[nb], 0, 0, 0);
  }
}

__global__ __launch_bounds__(256) void attn_kernel(
    const u16* __restrict__ Q, const u16* __restrict__ Kf, const u16* __restrict__ Vf,
    const float* __restrict__ SubP64, const float* __restrict__ X, float* __restrict__ out,
    const float* __restrict__ alphap, const float* __restrict__ betap,
    const float* __restrict__ gammap)
{
  // main phase: pbufF[4][16][68] f32 (17408 B); epilogue aliases:
  // Xt[64][68] (17408 B) + G[4][64] + GP[4][64] (2048 B)
  __shared__ __align__(16) char smem[19456];

  const int tid  = threadIdx.x;
  const int w    = tid >> 6;
  const int lane = tid & 63;
  const int quad = lane >> 4;
  const int l16  = lane & 15;
  const int qt = 31 - blockIdx.y;        // LPT
  const int bh = blockIdx.x;
  const int b = bh >> 4, h = bh & 15;

  const u16* kfb = Kf + (size_t)bh * T_ * HD_;
  const u16* vfb = Vf + (size_t)bh * T_ * HD_;

  bf16x8 qfrag[2];
  {
    const u16* qp = Q + ((size_t)bh * T_ + qt * 64 + w * 16 + l16) * HD_ + quad * 8;
    qfrag[0] = *(const bf16x8*)qp;
    qfrag[1] = *(const bf16x8*)(qp + 32);
  }

  bf16x8 onesf;
#pragma unroll
  for (int j = 0; j < 8; ++j) onesf[j] = (short)0x3F80;

  f32x4 zero = {0.f, 0.f, 0.f, 0.f};
  f32x4 acc[4] = {zero, zero, zero, zero};
  f32x4 accl = zero;
  const int myrow = w * 16 + quad * 4;
  float (*pb)[68] = (float(*)[68])((float*)smem + (size_t)w * 16 * 68);

  bf16x8 kA[2][4], vA[2][4], kB[2][4], vB[2][4];
  load_kv(kA, vA, kfb, vfb, lane);
  int kt = 0;
  for (;;) {
    int ktn = (kt + 1 < qt) ? kt + 1 : qt;
    load_kv(kB, vB, kfb + (size_t)ktn * 4096, vfb + (size_t)ktn * 4096, lane);
    tile_compute(qfrag, kA, vA, acc, accl, pb, quad, l16, myrow, kt == qt, onesf);
    if (kt + 1 > qt) break;
    int ktn2 = (kt + 2 < qt) ? kt + 2 : qt;
    load_kv(kA, vA, kfb + (size_t)ktn2 * 4096, vfb + (size_t)ktn2 * 4096, lane);
    tile_compute(qfrag, kB, vB, acc, accl, pb, quad, l16, myrow, kt + 1 == qt, onesf);
    kt += 2;
    if (kt > qt) break;
  }

  // ---------------- fused epilogue ----------------
  __syncthreads();                        // all waves done with pbufF
  float* Xt = (float*)smem;               // [64][68]
  float* G  = (float*)(smem + 17408);     // [4][64]
  float* GP = (float*)(smem + 18432);     // [4][64]

  {
    const int row = tid >> 2, c0 = (tid & 3) * 16;
    const float* xp = X + ((size_t)b * T_ + qt * 64 + row) * C_ + h * 64 + c0;
#pragma unroll
    for (int q = 0; q < 4; ++q) {
      float4 v = *(const float4*)(xp + q * 4);
      Xt[row * 68 + c0 + q * 4 + 0] = v.x;
      Xt[row * 68 + c0 + q * 4 + 1] = v.y;
      Xt[row * 68 + c0 + q * 4 + 2] = v.z;
      Xt[row * 68 + c0 + q * 4 + 3] = v.w;
    }
  }
  {
    float p = 0.f;
    for (int i = w; i < qt; i += 4)
      p += SubP64[(size_t)bh * 2048 + i * 64 + lane];
    GP[w * 64 + lane] = p;
  }
  __syncthreads();
  {
    float g = 0.f;
#pragma unroll
    for (int i = 0; i < 16; ++i) g += Xt[(w * 16 + i) * 68 + lane];
    G[w * 64 + lane] = g;
  }
  __syncthreads();
  {
    const float alpha = *alphap, gamma = *gammap;
    float run = GP[lane] + GP[64 + lane] + GP[128 + lane] + GP[192 + lane];
    for (int g = 0; g < w; ++g) run += G[g * 64 + lane];
    const int tbase = qt * 64 + w * 16;
#pragma unroll
    for (int i = 0; i < 16; ++i) {
      float v = Xt[(w * 16 + i) * 68 + lane];
      run += v;
      Xt[(w * 16 + i) * 68 + lane] =
          alpha * v - gamma * run * __builtin_amdgcn_rcpf((float)(tbase + i + 1));
    }
  }
  __syncthreads();

  const float beta = *betap;
  float rl[4];
#pragma unroll
  for (int r = 0; r < 4; ++r) rl[r] = beta * __builtin_amdgcn_rcpf(accl[r]);
#pragma unroll
  for (int nb = 0; nb < 4; ++nb) {
#pragma unroll
    for (int r = 0; r < 4; ++r) {
      int t = qt * 64 + myrow + r;
      int d = nb * 16 + l16;
      out[((size_t)b * T_ + t) * C_ + h * 64 + d] =
          Xt[(myrow + r) * 68 + d] + rl[r] * acc[nb][r];
    }
  }
}

// ---------------------------------------------------------------------------
extern "C" void kernel_launch(void* const* d_in, const int* in_sizes, int n_in,
                              void* d_out, int out_size, void* d_ws, size_t ws_size,
                              hipStream_t stream) {
  const float* x      = (const float*)d_in[0];
  const float* W_attn = (const float*)d_in[1];
  const float* alphap = (const float*)d_in[2];
  const float* betap  = (const float*)d_in[3];
  const float* gammap = (const float*)d_in[4];
  float* out = (float*)d_out;

  // ws: Qb@0(8M) Kf@8(8M) Vf@16(8M) SubP64@24(.25M) Xb@25(8M) Wb@33(4M) = 37M
  char* ws = (char*)d_ws;
  u16*   Qb     = (u16*)(ws);
  u16*   Kfb    = (u16*)(ws + (8ull  << 20));
  u16*   Vfb    = (u16*)(ws + (16ull << 20));
  float* SubP64 = (float*)(ws + (24ull << 20));
  u16*   Xb     = (u16*)(ws + (25ull << 20));
  u16*   Wb     = (u16*)(ws + (33ull << 20));

  prep<<<3072, 256, 0, stream>>>(x, W_attn, Xb, Wb, Vfb, SubP64);
  gemm_qk<<<dim3(16, 32), 256, 0, stream>>>(Xb, Wb, Qb, Kfb);
  attn_kernel<<<dim3(32, 32), 256, 0, stream>>>(Qb, Kfb, Vfb, SubP64, x, out,
                                                alphap, betap, gammap);
}